// Round 17
// baseline (3067.310 us; speedup 1.0000x reference)
//
#include <hip/hip_runtime.h>
#include <math.h>

// Fused ConvTranspose3d(32->64,k5,s2,p2) + sum(C_out) + bias + MaxPool(2) + MaxPool(3)
// x: (16,32,48,48,48) f32, weight: (32,64,5,5,5) f32, bias: (64,) f32
// out: (16,1,15,15,15) f32
//
// y[od] = sum x[id]*cw[kd], od = 2*id-2+kd; final out[j] = max over od in [6j,6j+5]^3 + cb.
// Window row r = 2*li + k - 4.
//
// ROUND 17: R16 (4-wave split + inline-asm dot2, lean schedule) failed correctness
// while the identical-logic R15 (spill schedule) passed -> codegen-level breakage
// tied to the inline asm under tight regalloc. This round keeps the 4-wave-split
// structure but uses the __builtin_amdgcn_fdot2 INTRINSIC (correct across R5-R13
// under every schedule), and simplifies to 256-thr single-tile blocks:
// LDS ~14KB -> 8 blocks x 4 waves = 32 waves/CU (HW max). Weights from global/L1
// (padded 48B rows). XCD swizzle + parity-uniform waves + pixel-major xt kept.

#define XS (48*48*48)

typedef __fp16 h2 __attribute__((ext_vector_type(2)));
union UH { unsigned u; h2 h; };

__device__ __forceinline__ unsigned pk16(float a, float b) {
    UH r; r.h = __builtin_amdgcn_cvt_pkrtz(a, b);  // v_cvt_pkrtz_f16_f32
    return r.u;
}

// ---------------- Kernel 1: fold weights over C_out, pack f16, padded rows ----------------
// ws layout (u32): [(kd*2+chunk)*4+cg][kh][12]: tap kw at [kw*2, kw*2+1] (2ch f16 pairs),
// slots 10,11 zero pad -> each kh-row is one 48B-aligned run of 3 dwordx4.
// ws[2400] (as float) = bias sum.   (unchanged from R15 -- passed correctness)
__global__ void fold_kernel(const float* __restrict__ w,
                            const float* __restrict__ bias,
                            unsigned* __restrict__ ws) {
    int t = blockIdx.x * blockDim.x + threadIdx.x;
    if (t < 2000) {
        int pix = t >> 4, sc = t & 15;
        int kd = pix / 25, r25 = pix % 25;
        int kh = r25 / 5,  kw = r25 % 5;
        int chunk = sc >> 3, lc = sc & 7;
        int cg = lc >> 1,    sub = lc & 1;
        const float* p0 = w + (size_t)(2 * sc) * 64 * 125 + pix;
        const float* p1 = p0 + 64 * 125;
        float s0 = 0.f, s1 = 0.f;
        #pragma unroll 8
        for (int o = 0; o < 64; ++o) { s0 += p0[o * 125]; s1 += p1[o * 125]; }
        ws[((((kd * 2 + chunk) * 4 + cg) * 5) + kh) * 12 + kw * 2 + sub] = pk16(s0, s1);
    } else if (t < 2400) {
        int i = t - 2000;                 // 200 rows x 2 pad slots
        ws[(i >> 1) * 12 + 10 + (i & 1)] = 0;
    } else if (t == 2400) {
        float s = 0.f;
        for (int o = 0; o < 64; ++o) s += bias[o];
        ((float*)ws)[2400] = s;
    }
}

union WR { uint4 q[3]; unsigned u[12]; };

// ---------------- Kernel 2: fused conv + maxpool ----------------
// Block = 256 thr = 1 tile x 4 waves. Wave = (wpar = rd parity, rwh = rw half).
// Lane: fo = lane/12 (0..4), rdi = (lane%12)>>2 (0..2), cg = lane&3; rd = 2*rdi+wpar.
// xt pixel-major: [425 px][8 u32 = 16ch f16 pairs]. Weights from global (L1-hot).
__global__ __launch_bounds__(256)
void fused_kernel(const float* __restrict__ x,
                  const unsigned* __restrict__ wsrc,
                  float* __restrict__ out) {
    __shared__ unsigned xt[425 * 8];          // 13.6 KB
    __shared__ float red[60];                 // [fo(5)][rd(6)][rwh(2)]

    const int tid = threadIdx.x;
    // XCD-chunked swizzle: grid 10800 = 8 x 1350
    int bid = ((blockIdx.x & 7) * 1350) + (blockIdx.x >> 3);
    const int bw = bid % 3;  bid /= 3;
    const int jh = bid % 15; bid /= 15;
    const int jd = bid % 15; const int n = bid / 15;
    const int d0 = 3 * jd - 1, h0 = 3 * jh - 1, w0 = 15 * bw - 1;

    // wave decode (4 waves)
    const int wid  = tid >> 6;          // 0..3
    const int wpar = wid & 1;           // rd parity
    const int rwh  = wid >> 1;          // rw half: rw in [3*rwh, 3*rwh+2]
    const int lane = tid & 63;
    const int fo   = lane / 12;         // 0..4 (lanes 60..63 idle in compute)
    const int rdi  = (lane % 12) >> 2;  // 0..2
    const int cg   = lane & 3;          // channel quad within 16-ch chunk
    const bool active = lane < 60;
    const int rd   = 2 * rdi + wpar;
    const int ntd  = wpar ? 2 : 3;      // wave-uniform tap-unit count

    // staging decode (all 256 threads)
    const int c2   = tid & 7;           // channel pair (2c2, 2c2+1)
    const int p00  = tid >> 3;          // 0..31

    float acc[18];                      // [rh 6][rwl 3]
    #pragma unroll
    for (int i = 0; i < 18; ++i) acc[i] = 0.f;

    for (int chunk = 0; chunk < 2; ++chunk) {
        __syncthreads();
        // stage 16 channels as f16 pairs, pixel-major (lane-contiguous writes)
        {
            const float* xc0 = x + ((size_t)n * 32 + chunk * 16 + 2 * c2) * XS;
            const float* xc1 = xc0 + XS;
            unsigned* xdst = &xt[c2];
            for (int p = p00; p < 425; p += 32) {
                int dz = p / 85;
                int rm = p - dz * 85;
                int dy = rm / 17;
                int dx = rm - dy * 17;
                int gd = d0 + dz, gh = h0 + dy, gw = w0 + dx;
                unsigned v = 0;
                if (((unsigned)gd < 48u) & ((unsigned)gh < 48u) & ((unsigned)gw < 48u)) {
                    int off = (gd * 48 + gh) * 48 + gw;
                    v = pk16(xc0[off], xc1[off]);
                }
                xdst[p * 8] = v;
            }
        }
        __syncthreads();

        if (active) {
            #pragma unroll
            for (int a = 0; a < 3; ++a) {
                if (a < ntd) {                       // wave-uniform branch
                    const int lid = rdi + 2 - a;     // d-slice in tile
                    const int kd  = wpar + 2 * a;    // d kernel tap

                    // ir base: this wave needs liw = rwh .. rwh+3
                    const unsigned* xb =
                        &xt[(lid * 85 + 3 * fo + rwh) * 8 + cg * 2];
                    // W rows for (kd, chunk, cg): 15 dwordx4, row kh = 3 of them
                    const uint4* wq = (const uint4*)wsrc +
                                      (size_t)((kd * 2 + chunk) * 4 + cg) * 15;

                    #pragma unroll
                    for (int lih = 0; lih < 5; ++lih) {
                        uint2 ir[4];                 // 4 pixels (liw = rwh+j)
                        #pragma unroll
                        for (int j = 0; j < 4; ++j)
                            ir[j] = *(const uint2*)&xb[(lih * 17 + j) * 8];
                        #pragma unroll
                        for (int kh = 0; kh < 5; ++kh) {
                            const int rh = 2 * lih + kh - 4;
                            if (rh >= 0 && rh < 6) {
                                WR W;                 // one 48B weight row (L1-hot)
                                W.q[0] = wq[kh * 3 + 0];
                                W.q[1] = wq[kh * 3 + 1];
                                W.q[2] = wq[kh * 3 + 2];
                                #pragma unroll
                                for (int j = 0; j < 4; ++j) {
                                    const int liw = rwh + j;
                                    #pragma unroll
                                    for (int kw = 0; kw < 5; ++kw) {
                                        const int rw = 2 * liw + kw - 4;
                                        if (rw >= 3 * rwh && rw < 3 * rwh + 3) {
                                            const int rwl = rw - 3 * rwh;
                                            UH x0, x1, w0v, w1v;
                                            x0.u  = ir[j].x;
                                            x1.u  = ir[j].y;
                                            w0v.u = W.u[kw * 2];
                                            w1v.u = W.u[kw * 2 + 1];
                                            float s = acc[rh * 3 + rwl];
                                            s = __builtin_amdgcn_fdot2(x0.h, w0v.h, s, false);
                                            s = __builtin_amdgcn_fdot2(x1.h, w1v.h, s, false);
                                            acc[rh * 3 + rwl] = s;
                                        }
                                    }
                                }
                            }
                        }
                    }
                }
            }
        }
    }

    // sum over cg (4 adjacent lanes), then max over the 6x3 slab
    if (active) {
        #pragma unroll
        for (int i = 0; i < 18; ++i) {
            acc[i] += __shfl_xor(acc[i], 1);
            acc[i] += __shfl_xor(acc[i], 2);
        }
        if (cg == 0) {
            float m = -INFINITY;
            #pragma unroll
            for (int i = 0; i < 18; ++i) m = fmaxf(m, acc[i]);
            red[(fo * 6 + rd) * 2 + rwh] = m;
        }
    }
    __syncthreads();
    if (tid < 5) {
        float m = -INFINITY;
        #pragma unroll
        for (int k = 0; k < 12; ++k)
            m = fmaxf(m, red[tid * 12 + k]);
        float cb = ((const float*)wsrc)[2400];
        out[(((size_t)n * 15 + jd) * 15 + jh) * 15 + 5 * bw + tid] = m + cb;
    }
}

extern "C" void kernel_launch(void* const* d_in, const int* in_sizes, int n_in,
                              void* d_out, int out_size, void* d_ws, size_t ws_size,
                              hipStream_t stream) {
    const float* x = (const float*)d_in[0];
    const float* w = (const float*)d_in[1];
    const float* b = (const float*)d_in[2];
    float* out = (float*)d_out;
    unsigned* ws = (unsigned*)d_ws;

    fold_kernel<<<10, 256, 0, stream>>>(w, b, ws);

    // grid: 3 bw x 15 jh x 15 jd x 16 n (XCD-swizzled in-kernel), 256 thr
    fused_kernel<<<3 * 15 * 15 * 16, 256, 0, stream>>>(x, ws, out);
}

// Round 18
// 298.838 us; speedup vs baseline: 10.2641x; 10.2641x over previous
//
#include <hip/hip_runtime.h>
#include <math.h>

// Fused ConvTranspose3d(32->64,k5,s2,p2) + sum(C_out) + bias + MaxPool(2) + MaxPool(3)
// x: (16,32,48,48,48) f32, weight: (32,64,5,5,5) f32, bias: (64,) f32
// out: (16,1,15,15,15) f32
//
// y[od] = sum x[id]*cw[kd], od = 2*id-2+kd; final out[j] = max over od in [6j,6j+5]^3 + cb.
// Window row r = 2*li + k - 4.
//
// ROUND 18: root cause of R15 (spill, 1686us), R16 (wrong results), R17 (17x VALU
// select-chain bloat, 3067us) is ONE bug: rwh (wave-id bits) made acc[rh*3+rwl] a
// RUNTIME-indexed register array (rule #20). Fix: template<int RWH> the chunk body,
// dispatch with one wave-uniform branch -> every register index compile-time.
// Live set ~50 regs -> lean 64-reg schedule is finally sufficient; LDS 14.3KB ->
// 8 blocks x 4 waves = 32 waves/CU. XCD swizzle + parity waves + pixel-major xt +
// fdot2 intrinsic + weights from global/L1 all kept from R17.

#define XS (48*48*48)

typedef __fp16 h2 __attribute__((ext_vector_type(2)));
union UH { unsigned u; h2 h; };

__device__ __forceinline__ unsigned pk16(float a, float b) {
    UH r; r.h = __builtin_amdgcn_cvt_pkrtz(a, b);  // v_cvt_pkrtz_f16_f32
    return r.u;
}

// ---------------- Kernel 1: fold weights over C_out, pack f16, padded rows ----------------
// ws layout (u32): [(kd*2+chunk)*4+cg][kh][12]: tap kw at [kw*2, kw*2+1] (2ch f16 pairs),
// slots 10,11 zero pad -> each kh-row is one 48B-aligned run of 3 dwordx4.
// ws[2400] (as float) = bias sum.
__global__ void fold_kernel(const float* __restrict__ w,
                            const float* __restrict__ bias,
                            unsigned* __restrict__ ws) {
    int t = blockIdx.x * blockDim.x + threadIdx.x;
    if (t < 2000) {
        int pix = t >> 4, sc = t & 15;
        int kd = pix / 25, r25 = pix % 25;
        int kh = r25 / 5,  kw = r25 % 5;
        int chunk = sc >> 3, lc = sc & 7;
        int cg = lc >> 1,    sub = lc & 1;
        const float* p0 = w + (size_t)(2 * sc) * 64 * 125 + pix;
        const float* p1 = p0 + 64 * 125;
        float s0 = 0.f, s1 = 0.f;
        #pragma unroll 8
        for (int o = 0; o < 64; ++o) { s0 += p0[o * 125]; s1 += p1[o * 125]; }
        ws[((((kd * 2 + chunk) * 4 + cg) * 5) + kh) * 12 + kw * 2 + sub] = pk16(s0, s1);
    } else if (t < 2400) {
        int i = t - 2000;                 // 200 rows x 2 pad slots
        ws[(i >> 1) * 12 + 10 + (i & 1)] = 0;
    } else if (t == 2400) {
        float s = 0.f;
        for (int o = 0; o < 64; ++o) s += bias[o];
        ((float*)ws)[2400] = s;
    }
}

union WR { uint4 q[3]; unsigned u[12]; };

// Compute one 16-ch chunk for one wave's (wpar, RWH) work split.
// ALL register indices compile-time (RWH is a template parameter).
template<int RWH>
__device__ __forceinline__ void compute_chunk(const unsigned* __restrict__ xt,
                                              const uint4* __restrict__ wbase,
                                              float* __restrict__ acc,
                                              int rdi, int wpar, int ntd,
                                              int fo, int cg, int chunk) {
    #pragma unroll
    for (int a = 0; a < 3; ++a) {
        if (a < ntd) {                       // wave-uniform branch
            const int lid = rdi + 2 - a;     // d-slice in tile (address only)
            const int kd  = wpar + 2 * a;    // d kernel tap   (address only)

            const unsigned* xb = &xt[(lid * 85 + 3 * fo + RWH) * 8 + cg * 2];
            const uint4* wq = wbase + (size_t)((kd * 2 + chunk) * 4 + cg) * 15;

            #pragma unroll
            for (int lih = 0; lih < 5; ++lih) {
                uint2 ir[4];                 // pixels liw = RWH .. RWH+3
                #pragma unroll
                for (int j = 0; j < 4; ++j)
                    ir[j] = *(const uint2*)&xb[(lih * 17 + j) * 8];
                #pragma unroll
                for (int kh = 0; kh < 5; ++kh) {
                    const int rh = 2 * lih + kh - 4;
                    if (rh >= 0 && rh < 6) {
                        WR W;                 // one 48B weight row (L1-hot)
                        W.q[0] = wq[kh * 3 + 0];
                        W.q[1] = wq[kh * 3 + 1];
                        W.q[2] = wq[kh * 3 + 2];
                        #pragma unroll
                        for (int j = 0; j < 4; ++j) {
                            const int liw = RWH + j;
                            #pragma unroll
                            for (int kw = 0; kw < 5; ++kw) {
                                const int rw = 2 * liw + kw - 4;
                                if (rw >= 3 * RWH && rw < 3 * RWH + 3) {
                                    const int rwl = rw - 3 * RWH;   // compile-time
                                    UH x0, x1, w0v, w1v;
                                    x0.u  = ir[j].x;
                                    x1.u  = ir[j].y;
                                    w0v.u = W.u[kw * 2];
                                    w1v.u = W.u[kw * 2 + 1];
                                    float s = acc[rh * 3 + rwl];
                                    s = __builtin_amdgcn_fdot2(x0.h, w0v.h, s, false);
                                    s = __builtin_amdgcn_fdot2(x1.h, w1v.h, s, false);
                                    acc[rh * 3 + rwl] = s;
                                }
                            }
                        }
                    }
                }
            }
        }
    }
}

// ---------------- Kernel 2: fused conv + maxpool ----------------
// Block = 256 thr = 1 tile x 4 waves. Wave = (wpar = rd parity, rwh = rw half).
// Lane: fo = lane/12 (0..4), rdi = (lane%12)>>2 (0..2), cg = lane&3; rd = 2*rdi+wpar.
// xt pixel-major: [425 px][8 u32 = 16ch f16 pairs]. Weights from global (L1-hot).
__global__ __launch_bounds__(256)
void fused_kernel(const float* __restrict__ x,
                  const unsigned* __restrict__ wsrc,
                  float* __restrict__ out) {
    __shared__ unsigned xt[425 * 8];          // 13.6 KB
    __shared__ float red[60];                 // [fo(5)][rd(6)][rwh(2)]

    const int tid = threadIdx.x;
    // XCD-chunked swizzle: grid 10800 = 8 x 1350
    int bid = ((blockIdx.x & 7) * 1350) + (blockIdx.x >> 3);
    const int bw = bid % 3;  bid /= 3;
    const int jh = bid % 15; bid /= 15;
    const int jd = bid % 15; const int n = bid / 15;
    const int d0 = 3 * jd - 1, h0 = 3 * jh - 1, w0 = 15 * bw - 1;

    // wave decode (4 waves)
    const int wid  = tid >> 6;          // 0..3
    const int wpar = wid & 1;           // rd parity
    const int rwh  = wid >> 1;          // rw half (dispatched to template below)
    const int lane = tid & 63;
    const int fo   = lane / 12;         // 0..4 (lanes 60..63 idle in compute)
    const int rdi  = (lane % 12) >> 2;  // 0..2
    const int cg   = lane & 3;          // channel quad within 16-ch chunk
    const bool active = lane < 60;
    const int rd   = 2 * rdi + wpar;
    const int ntd  = wpar ? 2 : 3;      // wave-uniform tap-unit count

    // staging decode (all 256 threads)
    const int c2   = tid & 7;           // channel pair (2c2, 2c2+1)
    const int p00  = tid >> 3;          // 0..31

    float acc[18];                      // [rh 6][rwl 3]
    #pragma unroll
    for (int i = 0; i < 18; ++i) acc[i] = 0.f;

    for (int chunk = 0; chunk < 2; ++chunk) {
        __syncthreads();
        // stage 16 channels as f16 pairs, pixel-major (lane-contiguous writes)
        {
            const float* xc0 = x + ((size_t)n * 32 + chunk * 16 + 2 * c2) * XS;
            const float* xc1 = xc0 + XS;
            unsigned* xdst = &xt[c2];
            for (int p = p00; p < 425; p += 32) {
                int dz = p / 85;
                int rm = p - dz * 85;
                int dy = rm / 17;
                int dx = rm - dy * 17;
                int gd = d0 + dz, gh = h0 + dy, gw = w0 + dx;
                unsigned v = 0;
                if (((unsigned)gd < 48u) & ((unsigned)gh < 48u) & ((unsigned)gw < 48u)) {
                    int off = (gd * 48 + gh) * 48 + gw;
                    v = pk16(xc0[off], xc1[off]);
                }
                xdst[p * 8] = v;
            }
        }
        __syncthreads();

        if (active) {
            if (rwh == 0)
                compute_chunk<0>(xt, (const uint4*)wsrc, acc,
                                 rdi, wpar, ntd, fo, cg, chunk);
            else
                compute_chunk<1>(xt, (const uint4*)wsrc, acc,
                                 rdi, wpar, ntd, fo, cg, chunk);
        }
    }

    // sum over cg (4 adjacent lanes), then max over the 6x3 slab
    if (active) {
        #pragma unroll
        for (int i = 0; i < 18; ++i) {
            acc[i] += __shfl_xor(acc[i], 1);
            acc[i] += __shfl_xor(acc[i], 2);
        }
        if (cg == 0) {
            float m = -INFINITY;
            #pragma unroll
            for (int i = 0; i < 18; ++i) m = fmaxf(m, acc[i]);
            red[(fo * 6 + rd) * 2 + rwh] = m;
        }
    }
    __syncthreads();
    if (tid < 5) {
        float m = -INFINITY;
        #pragma unroll
        for (int k = 0; k < 12; ++k)
            m = fmaxf(m, red[tid * 12 + k]);
        float cb = ((const float*)wsrc)[2400];
        out[(((size_t)n * 15 + jd) * 15 + jh) * 15 + 5 * bw + tid] = m + cb;
    }
}

extern "C" void kernel_launch(void* const* d_in, const int* in_sizes, int n_in,
                              void* d_out, int out_size, void* d_ws, size_t ws_size,
                              hipStream_t stream) {
    const float* x = (const float*)d_in[0];
    const float* w = (const float*)d_in[1];
    const float* b = (const float*)d_in[2];
    float* out = (float*)d_out;
    unsigned* ws = (unsigned*)d_ws;

    fold_kernel<<<10, 256, 0, stream>>>(w, b, ws);

    // grid: 3 bw x 15 jh x 15 jd x 16 n (XCD-swizzled in-kernel), 256 thr
    fused_kernel<<<3 * 15 * 15 * 16, 256, 0, stream>>>(x, ws, out);
}

// Round 19
// 215.537 us; speedup vs baseline: 14.2310x; 1.3865x over previous
//
#include <hip/hip_runtime.h>
#include <math.h>

// Fused ConvTranspose3d(32->64,k5,s2,p2) + sum(C_out) + bias + MaxPool(2) + MaxPool(3)
// x: (16,32,48,48,48) f32, weight: (32,64,5,5,5) f32, bias: (64,) f32
// out: (16,1,15,15,15) f32
//
// y[od] = sum x[id]*cw[kd], od = 2*id-2+kd; final out[j] = max over od in [6j,6j+5]^3 + cb.
// Window row r = 2*li + k - 4.
//
// ROUND 19 (= R14, best @227us, + one change): staging geometry (div/mod chains,
// 27 iters x 2 chunks x both tiles, ~1000 VALU cy/thread) is block-uniform --
// it depends only on (d0,h0,w0). Hoist into a shared LDS table goff[425] built
// once by all 256 threads; staging loop becomes ds_read_b32 + 2 loads + pk16 +
// ds_write (~8 insts vs ~18, 1-deep addr chain). Everything else R14 verbatim:
// 2 tiles x 2 parity waves, pixel-major xt, cg-major W in LDS, asm DOT2PAIR,
// XCD swizzle. LDS 35.8 -> 37.5KB, still 4 blocks/CU.

#define XS (48*48*48)

typedef __fp16 h2 __attribute__((ext_vector_type(2)));
union UH { unsigned u; h2 h; };

__device__ __forceinline__ unsigned pk16(float a, float b) {
    UH r; r.h = __builtin_amdgcn_cvt_pkrtz(a, b);  // v_cvt_pkrtz_f16_f32
    return r.u;
}

// exactly two v_dot2_f32_f16: acc += dot(ir.x, w0) + dot(ir.y, w1)
#define DOT2PAIR(ACC, IR, W0, W1)                                        \
    asm("v_dot2_f32_f16 %0, %1, %3, %0\n\t"                              \
        "v_dot2_f32_f16 %0, %2, %4, %0"                                  \
        : "+v"(ACC)                                                      \
        : "v"(IR.x), "v"(IR.y), "v"(W0), "v"(W1))

// ---------------- Kernel 1: fold weights over C_out, pack f16 cg-major ----------------
// ws layout (u32): [kd 0..4][chunk 0..1][cg 0..3][26 pairs]; pair = 2ch f16.
// pads [50,51] per 52-u32 block zeroed. ws[2080] (as float) = bias sum.
__global__ void fold_kernel(const float* __restrict__ w,
                            const float* __restrict__ bias,
                            unsigned* __restrict__ ws) {
    int t = blockIdx.x * blockDim.x + threadIdx.x;
    if (t < 2000) {
        int pix = t >> 4, sc = t & 15;
        int kd = pix / 25, r25 = pix % 25;
        int kh = r25 / 5,  kw = r25 % 5;
        int chunk = sc >> 3, lc = sc & 7;
        int cg = lc >> 1,    sub = lc & 1;
        const float* p0 = w + (size_t)(2 * sc) * 64 * 125 + pix;
        const float* p1 = p0 + 64 * 125;
        float s0 = 0.f, s1 = 0.f;
        #pragma unroll 8
        for (int o = 0; o < 64; ++o) { s0 += p0[o * 125]; s1 += p1[o * 125]; }
        ws[(((kd * 2 + chunk) * 4 + cg) * 52) + (kh * 5 + kw) * 2 + sub] = pk16(s0, s1);
    } else if (t < 2080) {
        int i = t - 2000;
        ws[(i >> 1) * 52 + 50 + (i & 1)] = 0;
    } else if (t == 2080) {
        float s = 0.f;
        for (int o = 0; o < 64; ++o) s += bias[o];
        ((float*)ws)[2080] = s;
    }
}

union WU { uint4 q; uint2 d[2]; unsigned u[4]; };

// ---------------- Kernel 2: fused conv + maxpool ----------------
// Block = 256 thr = 2 tiles (n-paired). Per tile: 2 waves; wave parity = rd parity.
// Lane: fo = lane/12 (0..4), rdi = (lane%12)>>2 (0..2), cg = lane&3; rd = 2*rdi+wpar.
// xt pixel-major: [tile][425 px][8 u32 = 16ch f16 pairs].
__global__ __launch_bounds__(256)
void fused_kernel(const float* __restrict__ x,
                  const unsigned* __restrict__ wsrc,
                  float* __restrict__ out) {
    __shared__ unsigned xt[2 * 425 * 8];      // 27.2 KB
    __shared__ unsigned cwS[2080];            // 8.32 KB (shared by both tiles)
    __shared__ int goff[425];                 // 1.7 KB block-uniform offsets (-1 = OOB)
    __shared__ float red[60];                 // [tile][fo(5)][rd(6)]

    const int tid = threadIdx.x;
    // XCD-chunked swizzle: grid 5400 = 8 x 675 (675 = full bw*jh*jd per n-pair)
    int bid = ((blockIdx.x & 7) * 675) + (blockIdx.x >> 3);
    const int bw = bid % 3;  bid /= 3;
    const int jh = bid % 15; bid /= 15;
    const int jd = bid % 15; const int nb = bid / 15;   // n-pair 0..7
    const int d0 = 3 * jd - 1, h0 = 3 * jh - 1, w0 = 15 * bw - 1;

    const int t    = tid >> 7;          // tile 0/1
    const int n    = nb * 2 + t;
    const int tid2 = tid & 127;

    // stage packed weights once (520 x b128, whole block)
    for (int e = tid; e < 520; e += 256)
        ((uint4*)cwS)[e] = ((const uint4*)wsrc)[e];

    // build block-uniform geometry table (2 iters/thread; replaces 54 div/mod
    // chains per thread in the staging loops)
    for (int p = tid; p < 425; p += 256) {
        int dz = p / 85;
        int rm = p - dz * 85;
        int dy = rm / 17;
        int dx = rm - dy * 17;
        int gd = d0 + dz, gh = h0 + dy, gw = w0 + dx;
        bool ok = ((unsigned)gd < 48u) & ((unsigned)gh < 48u) & ((unsigned)gw < 48u);
        goff[p] = ok ? ((gd * 48 + gh) * 48 + gw) : -1;
    }

    // compute-lane decode
    const int lane = tid & 63;
    const int wpar = (tid >> 6) & 1;    // rd parity of this wave
    const int fo   = lane / 12;         // 0..4 (lane 60..63 idle)
    const int rdi  = (lane % 12) >> 2;  // 0..2
    const int cg   = lane & 3;
    const bool active = lane < 60;
    const int rd   = 2 * rdi + wpar;
    const int ntd  = wpar ? 2 : 3;      // wave-uniform

    // staging-lane decode (per tile: 128 threads)
    const int c2   = tid2 & 7;          // channel pair (2c2, 2c2+1)
    const int p00  = tid2 >> 3;         // 0..15

    float acc[36];
    #pragma unroll
    for (int i = 0; i < 36; ++i) acc[i] = 0.f;

    for (int chunk = 0; chunk < 2; ++chunk) {
        __syncthreads();   // covers goff/cwS on iter 0, xt readers on iter 1
        // stage 16 channels as f16 pairs, pixel-major, offsets from goff
        {
            const float* xc0 = x + ((size_t)n * 32 + chunk * 16 + 2 * c2) * XS;
            const float* xc1 = xc0 + XS;
            unsigned* xdst = &xt[t * 3400 + c2];
            for (int p = p00; p < 425; p += 16) {
                int off = goff[p];
                int offc = off < 0 ? 0 : off;          // safe address
                float a = xc0[offc], b = xc1[offc];
                unsigned v = off < 0 ? 0u : pk16(a, b);
                xdst[p * 8] = v;
            }
        }
        __syncthreads();

        if (active) {
            #pragma unroll
            for (int a = 0; a < 3; ++a) {
                if (a < ntd) {                       // wave-uniform branch
                    const int lid = rdi + 2 - a;
                    const int kd  = wpar + 2 * a;

                    // weights for (kd, chunk, cg): 13 x b128 (broadcast within cg group)
                    WU W[13];
                    {
                        const uint4* wb = (const uint4*)&cwS[((kd * 2 + chunk) * 4 + cg) * 52];
                        #pragma unroll
                        for (int i = 0; i < 13; ++i) W[i].q = wb[i];
                    }

                    const unsigned* xb = &xt[t * 3400 + (lid * 85 + 3 * fo) * 8 + cg * 2];

                    #pragma unroll
                    for (int lih = 0; lih < 5; ++lih) {
                        uint2 ir[5];
                        #pragma unroll
                        for (int iw = 0; iw < 5; ++iw)
                            ir[iw] = *(const uint2*)&xb[(lih * 17 + iw) * 8];
                        #pragma unroll
                        for (int kh = 0; kh < 5; ++kh) {
                            const int rh = 2 * lih + kh - 4;
                            if (rh >= 0 && rh < 6) {
                                #pragma unroll
                                for (int liw = 0; liw < 5; ++liw) {
                                    #pragma unroll
                                    for (int kw = 0; kw < 5; ++kw) {
                                        const int rw = 2 * liw + kw - 4;
                                        if (rw >= 0 && rw < 6) {
                                            const int j2 = (kh * 5 + kw) * 2;
                                            DOT2PAIR(acc[rh * 6 + rw], ir[liw],
                                                     W[j2 >> 2].u[j2 & 3],
                                                     W[(j2 + 1) >> 2].u[(j2 + 1) & 3]);
                                        }
                                    }
                                }
                            }
                        }
                    }
                }
            }
        }
    }

    // sum over cg (4 adjacent lanes), then max over the 6x6 slab
    if (active) {
        #pragma unroll
        for (int i = 0; i < 36; ++i) {
            acc[i] += __shfl_xor(acc[i], 1);
            acc[i] += __shfl_xor(acc[i], 2);
        }
        if (cg == 0) {
            float m = -INFINITY;
            #pragma unroll
            for (int i = 0; i < 36; ++i) m = fmaxf(m, acc[i]);
            red[t * 30 + fo * 6 + rd] = m;
        }
    }
    __syncthreads();
    if (tid < 10) {
        const int tt = tid / 5, ff = tid % 5;
        float m = -INFINITY;
        #pragma unroll
        for (int k = 0; k < 6; ++k) m = fmaxf(m, red[tt * 30 + ff * 6 + k]);
        float cb = ((const float*)wsrc)[2080];
        out[(((size_t)(nb * 2 + tt) * 15 + jd) * 15 + jh) * 15 + 5 * bw + ff] = m + cb;
    }
}

extern "C" void kernel_launch(void* const* d_in, const int* in_sizes, int n_in,
                              void* d_out, int out_size, void* d_ws, size_t ws_size,
                              hipStream_t stream) {
    const float* x = (const float*)d_in[0];
    const float* w = (const float*)d_in[1];
    const float* b = (const float*)d_in[2];
    float* out = (float*)d_out;
    unsigned* ws = (unsigned*)d_ws;

    fold_kernel<<<9, 256, 0, stream>>>(w, b, ws);

    // grid: 3 bw x 15 jh x 15 jd x 8 n-pairs (XCD-swizzled in-kernel)
    fused_kernel<<<3 * 15 * 15 * 8, 256, 0, stream>>>(x, ws, out);
}